// Round 1
// baseline (836.248 us; speedup 1.0000x reference)
//
#include <hip/hip_runtime.h>
#include <stdint.h>

#define N_NODES 100000
#define N_EDGES 1600000
#define N_FEAT 512
#define N_HID 256
#define N_CLASS 40

typedef float f32x4 __attribute__((ext_vector_type(4)));
typedef __bf16 bf16x8 __attribute__((ext_vector_type(8)));
typedef unsigned short u16x4 __attribute__((ext_vector_type(4)));
typedef unsigned short u16x8 __attribute__((ext_vector_type(8)));

__device__ __forceinline__ unsigned short f2bf(float f) {
  unsigned int u = __float_as_uint(f);
  unsigned int r = (u + 0x7FFFu + ((u >> 16) & 1u)) >> 16;
  return (unsigned short)r;
}
__device__ __forceinline__ float bf2f(unsigned short s) {
  return __uint_as_float(((unsigned int)s) << 16);
}

// ---------------- weight transpose + bf16 convert ----------------
__global__ void k_w1t(const float* __restrict__ W1, unsigned short* __restrict__ W1t) {
  int gid = blockIdx.x * 256 + threadIdx.x;        // over N_HID*N_FEAT, W1t[n][k]
  if (gid >= N_HID * N_FEAT) return;
  int n = gid / N_FEAT, k = gid % N_FEAT;
  W1t[gid] = f2bf(W1[(long)k * N_HID + n]);
}

__global__ void k_w2t(const float* __restrict__ W2, unsigned short* __restrict__ W2t) {
  int gid = blockIdx.x * 256 + threadIdx.x;        // over 48*N_HID, W2t[n][k], pad n to 48
  if (gid >= 48 * N_HID) return;
  int n = gid / N_HID, k = gid % N_HID;
  W2t[gid] = (n < N_CLASS) ? f2bf(W2[(long)k * N_CLASS + n]) : (unsigned short)0;
}

// ---------------- CSR build ----------------
__global__ void k_hist(const int* __restrict__ ei, int* __restrict__ cnt) {
  int e = blockIdx.x * 256 + threadIdx.x;
  if (e < N_EDGES) atomicAdd(&cnt[ei[e]], 1);
}

__global__ __launch_bounds__(1024) void k_scan(const int* __restrict__ cnt,
                                               int* __restrict__ row_ptr,
                                               int* __restrict__ cursor) {
  __shared__ int part[1024];
  const int tid = threadIdx.x;
  const int CH = (N_NODES + 1023) / 1024;          // 98
  int s = tid * CH, e = s + CH; if (e > N_NODES) e = N_NODES; if (s > N_NODES) s = N_NODES;
  int acc = 0;
  for (int i = s; i < e; ++i) acc += cnt[i];
  part[tid] = acc;
  __syncthreads();
  for (int d = 1; d < 1024; d <<= 1) {
    int v = (tid >= d) ? part[tid - d] : 0;
    __syncthreads();
    part[tid] += v;
    __syncthreads();
  }
  int off = (tid == 0) ? 0 : part[tid - 1];
  for (int i = s; i < e; ++i) { row_ptr[i] = off; cursor[i] = off; off += cnt[i]; }
  if (tid == 1023) row_ptr[N_NODES] = off;
}

__global__ void k_scatter(const int* __restrict__ ei, const float* __restrict__ ew,
                          int* __restrict__ cursor, int2* __restrict__ cw) {
  int e = blockIdx.x * 256 + threadIdx.x;
  if (e >= N_EDGES) return;
  int r = ei[e];
  int pos = atomicAdd(&cursor[r], 1);
  cw[pos] = make_int2(ei[N_EDGES + e], __float_as_int(ew[e]));
}

// ---------------- GEMM1: H1 = bf16(X @ W1 + b1), MFMA ----------------
// 512 threads = 8 waves (2 m x 4 n), tile 128x256, BK=32
__global__ __launch_bounds__(512) void k_gemm1(const float* __restrict__ X,
                                               const unsigned short* __restrict__ W1t,
                                               const float* __restrict__ b1,
                                               unsigned short* __restrict__ H1) {
  __shared__ unsigned short As[128][32];
  __shared__ unsigned short Bs[256][32];
  const int t = threadIdx.x;
  const int lane = t & 63;
  const int wid = t >> 6;
  const int wm = wid >> 2, wn = wid & 3;
  const long m0 = (long)blockIdx.x * 128;

  f32x4 acc[4][4] = {};
  const int ar = t >> 2;
  const int ak = (t & 3) * 8;
  const long arow = m0 + ar;
  const bool avalid = arow < N_NODES;
  const float* xsrc = X + arow * N_FEAT + ak;
  const unsigned short* bsrc0 = W1t + (long)ar * N_FEAT + ak;
  const unsigned short* bsrc1 = W1t + (long)(ar + 128) * N_FEAT + ak;

  for (int k0 = 0; k0 < N_FEAT; k0 += 32) {
    __syncthreads();
    f32x4 x0 = {}, x1 = {};
    if (avalid) {
      x0 = *(const f32x4*)(xsrc + k0);
      x1 = *(const f32x4*)(xsrc + k0 + 4);
    }
    u16x8 ap;
    ap[0] = f2bf(x0[0]); ap[1] = f2bf(x0[1]); ap[2] = f2bf(x0[2]); ap[3] = f2bf(x0[3]);
    ap[4] = f2bf(x1[0]); ap[5] = f2bf(x1[1]); ap[6] = f2bf(x1[2]); ap[7] = f2bf(x1[3]);
    *(u16x8*)&As[ar][ak] = ap;
    *(u16x8*)&Bs[ar][ak]       = *(const u16x8*)(bsrc0 + k0);
    *(u16x8*)&Bs[ar + 128][ak] = *(const u16x8*)(bsrc1 + k0);
    __syncthreads();

    bf16x8 a[4], b[4];
    #pragma unroll
    for (int mt = 0; mt < 4; ++mt)
      a[mt] = *(const bf16x8*)&As[wm * 64 + mt * 16 + (lane & 15)][(lane >> 4) * 8];
    #pragma unroll
    for (int nt = 0; nt < 4; ++nt)
      b[nt] = *(const bf16x8*)&Bs[wn * 64 + nt * 16 + (lane & 15)][(lane >> 4) * 8];
    #pragma unroll
    for (int mt = 0; mt < 4; ++mt)
      #pragma unroll
      for (int nt = 0; nt < 4; ++nt)
        acc[mt][nt] = __builtin_amdgcn_mfma_f32_16x16x32_bf16(a[mt], b[nt], acc[mt][nt], 0, 0, 0);
  }

  #pragma unroll
  for (int nt = 0; nt < 4; ++nt) {
    int col = wn * 64 + nt * 16 + (lane & 15);
    float bias = b1[col];
    #pragma unroll
    for (int mt = 0; mt < 4; ++mt) {
      #pragma unroll
      for (int i = 0; i < 4; ++i) {
        long row = m0 + wm * 64 + mt * 16 + (lane >> 4) * 4 + i;
        if (row < N_NODES) H1[row * N_HID + col] = f2bf(acc[mt][nt][i] + bias);
      }
    }
  }
}

// ---------------- SPMM1 + relu: H1r = bf16(relu(A @ H1)) ----------------
__global__ __launch_bounds__(256) void k_spmm1(const int* __restrict__ row_ptr,
                                               const int2* __restrict__ cw,
                                               const unsigned short* __restrict__ H1,
                                               unsigned short* __restrict__ H1r) {
  int r = blockIdx.x * 4 + (threadIdx.x >> 6);
  int lane = threadIdx.x & 63;
  if (r >= N_NODES) return;
  int s = row_ptr[r], e = row_ptr[r + 1];
  float a0 = 0.f, a1 = 0.f, a2 = 0.f, a3 = 0.f;
  for (int i = s; i < e; ++i) {
    int2 cwv = cw[i];
    float w = __int_as_float(cwv.y);
    u16x4 hv = *(const u16x4*)(H1 + (long)cwv.x * N_HID + lane * 4);
    a0 += w * bf2f(hv[0]);
    a1 += w * bf2f(hv[1]);
    a2 += w * bf2f(hv[2]);
    a3 += w * bf2f(hv[3]);
  }
  u16x4 o;
  o[0] = f2bf(fmaxf(a0, 0.f));
  o[1] = f2bf(fmaxf(a1, 0.f));
  o[2] = f2bf(fmaxf(a2, 0.f));
  o[3] = f2bf(fmaxf(a3, 0.f));
  *(u16x4*)(H1r + (long)r * N_HID + lane * 4) = o;
}

// ---------------- GEMM2: H2 = H1r @ W2 + b2, MFMA, N padded to 48 ----------------
// 256 threads = 4 waves, tile 128x48, BK=32
__global__ __launch_bounds__(256) void k_gemm2(const unsigned short* __restrict__ H1r,
                                               const unsigned short* __restrict__ W2t,
                                               const float* __restrict__ b2,
                                               float* __restrict__ H2) {
  __shared__ unsigned short As[128][32];
  __shared__ unsigned short Bs[48][32];
  const int t = threadIdx.x;
  const int lane = t & 63;
  const int wid = t >> 6;                   // wave -> 32-row block
  const long m0 = (long)blockIdx.x * 128;
  f32x4 acc[2][3] = {};

  for (int k0 = 0; k0 < N_HID; k0 += 32) {
    __syncthreads();
    #pragma unroll
    for (int p = 0; p < 2; ++p) {
      int u = t + p * 256;
      int rr = u >> 2, kk = (u & 3) * 8;
      long gr = m0 + rr;
      u16x8 v = {};
      if (gr < N_NODES) v = *(const u16x8*)(H1r + gr * N_HID + k0 + kk);
      *(u16x8*)&As[rr][kk] = v;
    }
    if (t < 192) {
      int rr = t >> 2, kk = (t & 3) * 8;
      *(u16x8*)&Bs[rr][kk] = *(const u16x8*)(W2t + (long)rr * N_HID + k0 + kk);
    }
    __syncthreads();

    bf16x8 a[2], b[3];
    #pragma unroll
    for (int mt = 0; mt < 2; ++mt)
      a[mt] = *(const bf16x8*)&As[wid * 32 + mt * 16 + (lane & 15)][(lane >> 4) * 8];
    #pragma unroll
    for (int nt = 0; nt < 3; ++nt)
      b[nt] = *(const bf16x8*)&Bs[nt * 16 + (lane & 15)][(lane >> 4) * 8];
    #pragma unroll
    for (int mt = 0; mt < 2; ++mt)
      #pragma unroll
      for (int nt = 0; nt < 3; ++nt)
        acc[mt][nt] = __builtin_amdgcn_mfma_f32_16x16x32_bf16(a[mt], b[nt], acc[mt][nt], 0, 0, 0);
  }

  #pragma unroll
  for (int nt = 0; nt < 3; ++nt) {
    int col = nt * 16 + (lane & 15);
    if (col < N_CLASS) {
      float bias = b2[col];
      #pragma unroll
      for (int mt = 0; mt < 2; ++mt) {
        #pragma unroll
        for (int i = 0; i < 4; ++i) {
          long row = m0 + wid * 32 + mt * 16 + (lane >> 4) * 4 + i;
          if (row < N_NODES) H2[row * N_CLASS + col] = acc[mt][nt][i] + bias;
        }
      }
    }
  }
}

// ---------------- SPMM2: out = A @ H2 ----------------
__global__ __launch_bounds__(256) void k_spmm2(const int* __restrict__ row_ptr,
                                               const int2* __restrict__ cw,
                                               const float* __restrict__ H2,
                                               float* __restrict__ out) {
  int r = blockIdx.x * 4 + (threadIdx.x >> 6);
  int lane = threadIdx.x & 63;
  if (r >= N_NODES) return;
  int s = row_ptr[r], e = row_ptr[r + 1];
  float acc = 0.f;
  for (int i = s; i < e; ++i) {
    int2 cwv = cw[i];
    if (lane < N_CLASS) acc += __int_as_float(cwv.y) * H2[(long)cwv.x * N_CLASS + lane];
  }
  if (lane < N_CLASS) out[(long)r * N_CLASS + lane] = acc;
}

// ---------------- log_softmax, in-place on out ----------------
__global__ __launch_bounds__(256) void k_lsm(float* __restrict__ out) {
  int r = blockIdx.x * 4 + (threadIdx.x >> 6);
  int lane = threadIdx.x & 63;
  if (r >= N_NODES) return;
  float v = (lane < N_CLASS) ? out[(long)r * N_CLASS + lane] : -INFINITY;
  float m = v;
  #pragma unroll
  for (int d = 32; d > 0; d >>= 1) m = fmaxf(m, __shfl_xor(m, d));
  float ex = (lane < N_CLASS) ? __expf(v - m) : 0.f;
  float ssum = ex;
  #pragma unroll
  for (int d = 32; d > 0; d >>= 1) ssum += __shfl_xor(ssum, d);
  float ls = __logf(ssum);
  if (lane < N_CLASS) out[(long)r * N_CLASS + lane] = v - m - ls;
}

extern "C" void kernel_launch(void* const* d_in, const int* in_sizes, int n_in,
                              void* d_out, int out_size, void* d_ws, size_t ws_size,
                              hipStream_t stream) {
  (void)in_sizes; (void)n_in; (void)out_size; (void)ws_size;
  const float* X  = (const float*)d_in[0];
  const int*   EI = (const int*)d_in[1];
  const float* EW = (const float*)d_in[2];
  const float* W1 = (const float*)d_in[3];
  const float* b1 = (const float*)d_in[4];
  const float* W2 = (const float*)d_in[5];
  const float* b2 = (const float*)d_in[6];
  float* out = (float*)d_out;

  char* p = (char*)d_ws;
  auto take = [&](size_t bytes) {
    char* r = p;
    p += (bytes + 511) & ~(size_t)511;
    return r;
  };
  unsigned short* W1t   = (unsigned short*)take((size_t)N_HID * N_FEAT * 2);
  unsigned short* W2t   = (unsigned short*)take((size_t)48 * N_HID * 2);
  int*            cnt   = (int*)take((size_t)N_NODES * 4);
  int*            rp    = (int*)take((size_t)(N_NODES + 1) * 4);
  int*            cur   = (int*)take((size_t)(N_NODES + 1) * 4);
  int2*           cw    = (int2*)take((size_t)N_EDGES * 8);
  unsigned short* H1    = (unsigned short*)take((size_t)N_NODES * N_HID * 2);
  unsigned short* H1r   = (unsigned short*)take((size_t)N_NODES * N_HID * 2);
  float*          H2    = (float*)take((size_t)N_NODES * N_CLASS * 4);

  hipMemsetAsync(cnt, 0, (size_t)N_NODES * 4, stream);
  k_w1t<<<(N_HID * N_FEAT + 255) / 256, 256, 0, stream>>>(W1, W1t);
  k_w2t<<<(48 * N_HID + 255) / 256, 256, 0, stream>>>(W2, W2t);
  k_hist<<<(N_EDGES + 255) / 256, 256, 0, stream>>>(EI, cnt);
  k_scan<<<1, 1024, 0, stream>>>(cnt, rp, cur);
  k_scatter<<<(N_EDGES + 255) / 256, 256, 0, stream>>>(EI, EW, cur, cw);
  k_gemm1<<<(N_NODES + 127) / 128, 512, 0, stream>>>(X, W1t, b1, H1);
  k_spmm1<<<(N_NODES + 3) / 4, 256, 0, stream>>>(rp, cw, H1, H1r);
  k_gemm2<<<(N_NODES + 127) / 128, 256, 0, stream>>>(H1r, W2t, b2, H2);
  k_spmm2<<<(N_NODES + 3) / 4, 256, 0, stream>>>(rp, cw, H2, out);
  k_lsm<<<(N_NODES + 3) / 4, 256, 0, stream>>>(out);
}

// Round 2
// 603.966 us; speedup vs baseline: 1.3846x; 1.3846x over previous
//
#include <hip/hip_runtime.h>
#include <stdint.h>

#define N_NODES 100000
#define N_EDGES 1600000
#define N_FEAT 512
#define N_HID 256
#define N_CLASS 40

typedef float f32x4 __attribute__((ext_vector_type(4)));
typedef __bf16 bf16x8 __attribute__((ext_vector_type(8)));
typedef unsigned short u16x4 __attribute__((ext_vector_type(4)));
typedef unsigned short u16x8 __attribute__((ext_vector_type(8)));

__device__ __forceinline__ unsigned short f2bf(float f) {
  unsigned int u = __float_as_uint(f);
  unsigned int r = (u + 0x7FFFu + ((u >> 16) & 1u)) >> 16;
  return (unsigned short)r;
}
__device__ __forceinline__ float bf2f(unsigned short s) {
  return __uint_as_float(((unsigned int)s) << 16);
}

// ---------------- weight transpose + bf16 convert ----------------
__global__ void k_w1t(const float* __restrict__ W1, unsigned short* __restrict__ W1t) {
  int gid = blockIdx.x * 256 + threadIdx.x;        // over N_HID*N_FEAT, W1t[n][k]
  if (gid >= N_HID * N_FEAT) return;
  int n = gid / N_FEAT, k = gid % N_FEAT;
  W1t[gid] = f2bf(W1[(long)k * N_HID + n]);
}

__global__ void k_w2t(const float* __restrict__ W2, unsigned short* __restrict__ W2t) {
  int gid = blockIdx.x * 256 + threadIdx.x;        // over 48*N_HID, W2t[n][k], pad n to 48
  if (gid >= 48 * N_HID) return;
  int n = gid / N_HID, k = gid % N_HID;
  W2t[gid] = (n < N_CLASS) ? f2bf(W2[(long)k * N_CLASS + n]) : (unsigned short)0;
}

// ---------------- CSR build ----------------
__global__ void k_hist(const int* __restrict__ ei, int* __restrict__ cnt) {
  int e = blockIdx.x * 256 + threadIdx.x;
  if (e < N_EDGES) atomicAdd(&cnt[ei[e]], 1);
}

// pass a: block-local exclusive scan of 1024 counts, local result -> rp, block sum -> bsum
__global__ __launch_bounds__(1024) void k_scan_a(const int* __restrict__ cnt,
                                                 int* __restrict__ rp,
                                                 int* __restrict__ bsum) {
  __shared__ int sm[1024];
  const int tid = threadIdx.x;
  const int i = blockIdx.x * 1024 + tid;
  int v = (i < N_NODES) ? cnt[i] : 0;
  sm[tid] = v;
  __syncthreads();
  #pragma unroll
  for (int d = 1; d < 1024; d <<= 1) {
    int t = (tid >= d) ? sm[tid - d] : 0;
    __syncthreads();
    sm[tid] += t;
    __syncthreads();
  }
  if (i < N_NODES) rp[i] = sm[tid] - v;            // local exclusive
  if (tid == 1023) bsum[blockIdx.x] = sm[1023];
}

// pass b: scan 98 block sums (exclusive) + write total
__global__ __launch_bounds__(128) void k_scan_b(const int* __restrict__ bsum,
                                                int* __restrict__ boffs,
                                                int* __restrict__ rp) {
  __shared__ int sm[128];
  const int tid = threadIdx.x;
  const int nb = (N_NODES + 1023) >> 10;           // 98
  int v = (tid < nb) ? bsum[tid] : 0;
  sm[tid] = v;
  __syncthreads();
  #pragma unroll
  for (int d = 1; d < 128; d <<= 1) {
    int t = (tid >= d) ? sm[tid - d] : 0;
    __syncthreads();
    sm[tid] += t;
    __syncthreads();
  }
  boffs[tid] = sm[tid] - v;
  if (tid == 127) rp[N_NODES] = sm[127];
}

// pass c: add block offsets; init cursor
__global__ void k_scan_c(int* __restrict__ rp, int* __restrict__ cur,
                         const int* __restrict__ boffs) {
  int i = blockIdx.x * 256 + threadIdx.x;
  if (i >= N_NODES) return;
  int v = rp[i] + boffs[i >> 10];
  rp[i] = v;
  cur[i] = v;
}

__global__ void k_scatter(const int* __restrict__ ei, const float* __restrict__ ew,
                          int* __restrict__ cursor, int2* __restrict__ cw) {
  int e = blockIdx.x * 256 + threadIdx.x;
  if (e >= N_EDGES) return;
  int r = ei[e];
  int pos = atomicAdd(&cursor[r], 1);
  cw[pos] = make_int2(ei[N_EDGES + e], __float_as_int(ew[e]));
}

// ---------------- GEMM1: H1 = bf16(X @ W1 + b1), MFMA ----------------
// 512 threads = 8 waves (2 m x 4 n), tile 128x256, BK=32
__global__ __launch_bounds__(512) void k_gemm1(const float* __restrict__ X,
                                               const unsigned short* __restrict__ W1t,
                                               const float* __restrict__ b1,
                                               unsigned short* __restrict__ H1) {
  __shared__ unsigned short As[128][32];
  __shared__ unsigned short Bs[256][32];
  const int t = threadIdx.x;
  const int lane = t & 63;
  const int wid = t >> 6;
  const int wm = wid >> 2, wn = wid & 3;
  const long m0 = (long)blockIdx.x * 128;

  f32x4 acc[4][4] = {};
  const int ar = t >> 2;
  const int ak = (t & 3) * 8;
  const long arow = m0 + ar;
  const bool avalid = arow < N_NODES;
  const float* xsrc = X + arow * N_FEAT + ak;
  const unsigned short* bsrc0 = W1t + (long)ar * N_FEAT + ak;
  const unsigned short* bsrc1 = W1t + (long)(ar + 128) * N_FEAT + ak;

  for (int k0 = 0; k0 < N_FEAT; k0 += 32) {
    __syncthreads();
    f32x4 x0 = {}, x1 = {};
    if (avalid) {
      x0 = *(const f32x4*)(xsrc + k0);
      x1 = *(const f32x4*)(xsrc + k0 + 4);
    }
    u16x8 ap;
    ap[0] = f2bf(x0[0]); ap[1] = f2bf(x0[1]); ap[2] = f2bf(x0[2]); ap[3] = f2bf(x0[3]);
    ap[4] = f2bf(x1[0]); ap[5] = f2bf(x1[1]); ap[6] = f2bf(x1[2]); ap[7] = f2bf(x1[3]);
    *(u16x8*)&As[ar][ak] = ap;
    *(u16x8*)&Bs[ar][ak]       = *(const u16x8*)(bsrc0 + k0);
    *(u16x8*)&Bs[ar + 128][ak] = *(const u16x8*)(bsrc1 + k0);
    __syncthreads();

    bf16x8 a[4], b[4];
    #pragma unroll
    for (int mt = 0; mt < 4; ++mt)
      a[mt] = *(const bf16x8*)&As[wm * 64 + mt * 16 + (lane & 15)][(lane >> 4) * 8];
    #pragma unroll
    for (int nt = 0; nt < 4; ++nt)
      b[nt] = *(const bf16x8*)&Bs[wn * 64 + nt * 16 + (lane & 15)][(lane >> 4) * 8];
    #pragma unroll
    for (int mt = 0; mt < 4; ++mt)
      #pragma unroll
      for (int nt = 0; nt < 4; ++nt)
        acc[mt][nt] = __builtin_amdgcn_mfma_f32_16x16x32_bf16(a[mt], b[nt], acc[mt][nt], 0, 0, 0);
  }

  #pragma unroll
  for (int nt = 0; nt < 4; ++nt) {
    int col = wn * 64 + nt * 16 + (lane & 15);
    float bias = b1[col];
    #pragma unroll
    for (int mt = 0; mt < 4; ++mt) {
      #pragma unroll
      for (int i = 0; i < 4; ++i) {
        long row = m0 + wm * 64 + mt * 16 + (lane >> 4) * 4 + i;
        if (row < N_NODES) H1[row * N_HID + col] = f2bf(acc[mt][nt][i] + bias);
      }
    }
  }
}

// ---------------- SPMM1 + relu: H1r = bf16(relu(A @ H1)) ----------------
__global__ __launch_bounds__(256) void k_spmm1(const int* __restrict__ row_ptr,
                                               const int2* __restrict__ cw,
                                               const unsigned short* __restrict__ H1,
                                               unsigned short* __restrict__ H1r) {
  int r = blockIdx.x * 4 + (threadIdx.x >> 6);
  int lane = threadIdx.x & 63;
  if (r >= N_NODES) return;
  int s = row_ptr[r], e = row_ptr[r + 1];
  float a0 = 0.f, a1 = 0.f, a2 = 0.f, a3 = 0.f;
  for (int i = s; i < e; ++i) {
    int2 cwv = cw[i];
    float w = __int_as_float(cwv.y);
    u16x4 hv = *(const u16x4*)(H1 + (long)cwv.x * N_HID + lane * 4);
    a0 += w * bf2f(hv[0]);
    a1 += w * bf2f(hv[1]);
    a2 += w * bf2f(hv[2]);
    a3 += w * bf2f(hv[3]);
  }
  u16x4 o;
  o[0] = f2bf(fmaxf(a0, 0.f));
  o[1] = f2bf(fmaxf(a1, 0.f));
  o[2] = f2bf(fmaxf(a2, 0.f));
  o[3] = f2bf(fmaxf(a3, 0.f));
  *(u16x4*)(H1r + (long)r * N_HID + lane * 4) = o;
}

// ---------------- GEMM2: H2 = H1r @ W2 + b2, MFMA, N padded to 48 ----------------
// 256 threads = 4 waves, tile 128x48, BK=32
__global__ __launch_bounds__(256) void k_gemm2(const unsigned short* __restrict__ H1r,
                                               const unsigned short* __restrict__ W2t,
                                               const float* __restrict__ b2,
                                               float* __restrict__ H2) {
  __shared__ unsigned short As[128][32];
  __shared__ unsigned short Bs[48][32];
  const int t = threadIdx.x;
  const int lane = t & 63;
  const int wid = t >> 6;                   // wave -> 32-row block
  const long m0 = (long)blockIdx.x * 128;
  f32x4 acc[2][3] = {};

  for (int k0 = 0; k0 < N_HID; k0 += 32) {
    __syncthreads();
    #pragma unroll
    for (int p = 0; p < 2; ++p) {
      int u = t + p * 256;
      int rr = u >> 2, kk = (u & 3) * 8;
      long gr = m0 + rr;
      u16x8 v = {};
      if (gr < N_NODES) v = *(const u16x8*)(H1r + gr * N_HID + k0 + kk);
      *(u16x8*)&As[rr][kk] = v;
    }
    if (t < 192) {
      int rr = t >> 2, kk = (t & 3) * 8;
      *(u16x8*)&Bs[rr][kk] = *(const u16x8*)(W2t + (long)rr * N_HID + k0 + kk);
    }
    __syncthreads();

    bf16x8 a[2], b[3];
    #pragma unroll
    for (int mt = 0; mt < 2; ++mt)
      a[mt] = *(const bf16x8*)&As[wid * 32 + mt * 16 + (lane & 15)][(lane >> 4) * 8];
    #pragma unroll
    for (int nt = 0; nt < 3; ++nt)
      b[nt] = *(const bf16x8*)&Bs[nt * 16 + (lane & 15)][(lane >> 4) * 8];
    #pragma unroll
    for (int mt = 0; mt < 2; ++mt)
      #pragma unroll
      for (int nt = 0; nt < 3; ++nt)
        acc[mt][nt] = __builtin_amdgcn_mfma_f32_16x16x32_bf16(a[mt], b[nt], acc[mt][nt], 0, 0, 0);
  }

  #pragma unroll
  for (int nt = 0; nt < 3; ++nt) {
    int col = nt * 16 + (lane & 15);
    if (col < N_CLASS) {
      float bias = b2[col];
      #pragma unroll
      for (int mt = 0; mt < 2; ++mt) {
        #pragma unroll
        for (int i = 0; i < 4; ++i) {
          long row = m0 + wid * 32 + mt * 16 + (lane >> 4) * 4 + i;
          if (row < N_NODES) H2[row * N_CLASS + col] = acc[mt][nt][i] + bias;
        }
      }
    }
  }
}

// ---------------- SPMM2 + log_softmax fused: out = log_softmax(A @ H2) ----------------
__global__ __launch_bounds__(256) void k_spmm2_lsm(const int* __restrict__ row_ptr,
                                                   const int2* __restrict__ cw,
                                                   const float* __restrict__ H2,
                                                   float* __restrict__ out) {
  int r = blockIdx.x * 4 + (threadIdx.x >> 6);
  int lane = threadIdx.x & 63;
  if (r >= N_NODES) return;
  int s = row_ptr[r], e = row_ptr[r + 1];
  float acc = 0.f;
  for (int i = s; i < e; ++i) {
    int2 cwv = cw[i];
    if (lane < N_CLASS) acc += __int_as_float(cwv.y) * H2[(long)cwv.x * N_CLASS + lane];
  }
  float v = (lane < N_CLASS) ? acc : -INFINITY;
  float m = v;
  #pragma unroll
  for (int d = 32; d > 0; d >>= 1) m = fmaxf(m, __shfl_xor(m, d));
  float ex = (lane < N_CLASS) ? __expf(v - m) : 0.f;
  float ssum = ex;
  #pragma unroll
  for (int d = 32; d > 0; d >>= 1) ssum += __shfl_xor(ssum, d);
  float ls = __logf(ssum);
  if (lane < N_CLASS) out[(long)r * N_CLASS + lane] = v - m - ls;
}

extern "C" void kernel_launch(void* const* d_in, const int* in_sizes, int n_in,
                              void* d_out, int out_size, void* d_ws, size_t ws_size,
                              hipStream_t stream) {
  (void)in_sizes; (void)n_in; (void)out_size; (void)ws_size;
  const float* X  = (const float*)d_in[0];
  const int*   EI = (const int*)d_in[1];
  const float* EW = (const float*)d_in[2];
  const float* W1 = (const float*)d_in[3];
  const float* b1 = (const float*)d_in[4];
  const float* W2 = (const float*)d_in[5];
  const float* b2 = (const float*)d_in[6];
  float* out = (float*)d_out;

  char* p = (char*)d_ws;
  auto take = [&](size_t bytes) {
    char* r = p;
    p += (bytes + 511) & ~(size_t)511;
    return r;
  };
  unsigned short* W1t   = (unsigned short*)take((size_t)N_HID * N_FEAT * 2);
  unsigned short* W2t   = (unsigned short*)take((size_t)48 * N_HID * 2);
  int*            cnt   = (int*)take((size_t)N_NODES * 4);
  int*            rp    = (int*)take((size_t)(N_NODES + 1) * 4);
  int*            cur   = (int*)take((size_t)(N_NODES + 1) * 4);
  int*            bsum  = (int*)take((size_t)128 * 4);
  int*            boffs = (int*)take((size_t)128 * 4);
  int2*           cw    = (int2*)take((size_t)N_EDGES * 8);
  unsigned short* H1    = (unsigned short*)take((size_t)N_NODES * N_HID * 2);
  unsigned short* H1r   = (unsigned short*)take((size_t)N_NODES * N_HID * 2);
  float*          H2    = (float*)take((size_t)N_NODES * N_CLASS * 4);

  const int NB_SCAN = (N_NODES + 1023) / 1024;     // 98

  hipMemsetAsync(cnt, 0, (size_t)N_NODES * 4, stream);
  k_w1t<<<(N_HID * N_FEAT + 255) / 256, 256, 0, stream>>>(W1, W1t);
  k_w2t<<<(48 * N_HID + 255) / 256, 256, 0, stream>>>(W2, W2t);
  k_hist<<<(N_EDGES + 255) / 256, 256, 0, stream>>>(EI, cnt);
  k_scan_a<<<NB_SCAN, 1024, 0, stream>>>(cnt, rp, bsum);
  k_scan_b<<<1, 128, 0, stream>>>(bsum, boffs, rp);
  k_scan_c<<<(N_NODES + 255) / 256, 256, 0, stream>>>(rp, cur, boffs);
  k_scatter<<<(N_EDGES + 255) / 256, 256, 0, stream>>>(EI, EW, cur, cw);
  k_gemm1<<<(N_NODES + 127) / 128, 512, 0, stream>>>(X, W1t, b1, H1);
  k_spmm1<<<(N_NODES + 3) / 4, 256, 0, stream>>>(rp, cw, H1, H1r);
  k_gemm2<<<(N_NODES + 127) / 128, 256, 0, stream>>>(H1r, W2t, b2, H2);
  k_spmm2_lsm<<<(N_NODES + 3) / 4, 256, 0, stream>>>(rp, cw, H2, out);
}

// Round 3
// 471.936 us; speedup vs baseline: 1.7720x; 1.2798x over previous
//
#include <hip/hip_runtime.h>
#include <stdint.h>

#define N_NODES 100000
#define N_EDGES 1600000
#define N_FEAT 512
#define N_HID 256
#define N_CLASS 40

typedef float f32x4 __attribute__((ext_vector_type(4)));
typedef __bf16 bf16x8 __attribute__((ext_vector_type(8)));
typedef unsigned short u16x4 __attribute__((ext_vector_type(4)));
typedef unsigned short u16x8 __attribute__((ext_vector_type(8)));

__device__ __forceinline__ unsigned short f2bf(float f) {
  unsigned int u = __float_as_uint(f);
  unsigned int r = (u + 0x7FFFu + ((u >> 16) & 1u)) >> 16;
  return (unsigned short)r;
}
__device__ __forceinline__ float bf2f(unsigned short s) {
  return __uint_as_float(((unsigned int)s) << 16);
}

// ---------------- weight transpose + bf16 convert ----------------
__global__ void k_w1t(const float* __restrict__ W1, unsigned short* __restrict__ W1t) {
  int gid = blockIdx.x * 256 + threadIdx.x;        // over N_HID*N_FEAT, W1t[n][k]
  if (gid >= N_HID * N_FEAT) return;
  int n = gid / N_FEAT, k = gid % N_FEAT;
  W1t[gid] = f2bf(W1[(long)k * N_HID + n]);
}

__global__ void k_w2t(const float* __restrict__ W2, unsigned short* __restrict__ W2t) {
  int gid = blockIdx.x * 256 + threadIdx.x;        // over 48*N_HID, W2t[n][k], pad n to 48
  if (gid >= 48 * N_HID) return;
  int n = gid / N_HID, k = gid % N_HID;
  W2t[gid] = (n < N_CLASS) ? f2bf(W2[(long)k * N_CLASS + n]) : (unsigned short)0;
}

// ---------------- CSR build ----------------
__global__ void k_hist(const int* __restrict__ ei, int* __restrict__ cnt) {
  int e = blockIdx.x * 256 + threadIdx.x;
  if (e < N_EDGES) atomicAdd(&cnt[ei[e]], 1);
}

// pass a: block-local exclusive scan of 1024 counts, local result -> rp, block sum -> bsum
__global__ __launch_bounds__(1024) void k_scan_a(const int* __restrict__ cnt,
                                                 int* __restrict__ rp,
                                                 int* __restrict__ bsum) {
  __shared__ int sm[1024];
  const int tid = threadIdx.x;
  const int i = blockIdx.x * 1024 + tid;
  int v = (i < N_NODES) ? cnt[i] : 0;
  sm[tid] = v;
  __syncthreads();
  #pragma unroll
  for (int d = 1; d < 1024; d <<= 1) {
    int t = (tid >= d) ? sm[tid - d] : 0;
    __syncthreads();
    sm[tid] += t;
    __syncthreads();
  }
  if (i < N_NODES) rp[i] = sm[tid] - v;            // local exclusive
  if (tid == 1023) bsum[blockIdx.x] = sm[1023];
}

// pass b: scan 98 block sums (exclusive) + write total
__global__ __launch_bounds__(128) void k_scan_b(const int* __restrict__ bsum,
                                                int* __restrict__ boffs,
                                                int* __restrict__ rp) {
  __shared__ int sm[128];
  const int tid = threadIdx.x;
  const int nb = (N_NODES + 1023) >> 10;           // 98
  int v = (tid < nb) ? bsum[tid] : 0;
  sm[tid] = v;
  __syncthreads();
  #pragma unroll
  for (int d = 1; d < 128; d <<= 1) {
    int t = (tid >= d) ? sm[tid - d] : 0;
    __syncthreads();
    sm[tid] += t;
    __syncthreads();
  }
  boffs[tid] = sm[tid] - v;
  if (tid == 127) rp[N_NODES] = sm[127];
}

// pass c: add block offsets; init cursor
__global__ void k_scan_c(int* __restrict__ rp, int* __restrict__ cur,
                         const int* __restrict__ boffs) {
  int i = blockIdx.x * 256 + threadIdx.x;
  if (i >= N_NODES) return;
  int v = rp[i] + boffs[i >> 10];
  rp[i] = v;
  cur[i] = v;
}

__global__ void k_scatter(const int* __restrict__ ei, const float* __restrict__ ew,
                          int* __restrict__ cursor, int2* __restrict__ cw) {
  int e = blockIdx.x * 256 + threadIdx.x;
  if (e >= N_EDGES) return;
  int r = ei[e];
  int pos = atomicAdd(&cursor[r], 1);
  cw[pos] = make_int2(ei[N_EDGES + e], __float_as_int(ew[e]));
}

// ---------------- GEMM1: H1 = bf16(X @ W1 + b1), MFMA ----------------
// 512 threads = 8 waves (2 m x 4 n), tile 128x256, BK=32
__global__ __launch_bounds__(512) void k_gemm1(const float* __restrict__ X,
                                               const unsigned short* __restrict__ W1t,
                                               const float* __restrict__ b1,
                                               unsigned short* __restrict__ H1) {
  __shared__ unsigned short As[128][32];
  __shared__ unsigned short Bs[256][32];
  const int t = threadIdx.x;
  const int lane = t & 63;
  const int wid = t >> 6;
  const int wm = wid >> 2, wn = wid & 3;
  const long m0 = (long)blockIdx.x * 128;

  f32x4 acc[4][4] = {};
  const int ar = t >> 2;
  const int ak = (t & 3) * 8;
  const long arow = m0 + ar;
  const bool avalid = arow < N_NODES;
  const float* xsrc = X + arow * N_FEAT + ak;
  const unsigned short* bsrc0 = W1t + (long)ar * N_FEAT + ak;
  const unsigned short* bsrc1 = W1t + (long)(ar + 128) * N_FEAT + ak;

  for (int k0 = 0; k0 < N_FEAT; k0 += 32) {
    __syncthreads();
    f32x4 x0 = {}, x1 = {};
    if (avalid) {
      x0 = *(const f32x4*)(xsrc + k0);
      x1 = *(const f32x4*)(xsrc + k0 + 4);
    }
    u16x8 ap;
    ap[0] = f2bf(x0[0]); ap[1] = f2bf(x0[1]); ap[2] = f2bf(x0[2]); ap[3] = f2bf(x0[3]);
    ap[4] = f2bf(x1[0]); ap[5] = f2bf(x1[1]); ap[6] = f2bf(x1[2]); ap[7] = f2bf(x1[3]);
    *(u16x8*)&As[ar][ak] = ap;
    *(u16x8*)&Bs[ar][ak]       = *(const u16x8*)(bsrc0 + k0);
    *(u16x8*)&Bs[ar + 128][ak] = *(const u16x8*)(bsrc1 + k0);
    __syncthreads();

    bf16x8 a[4], b[4];
    #pragma unroll
    for (int mt = 0; mt < 4; ++mt)
      a[mt] = *(const bf16x8*)&As[wm * 64 + mt * 16 + (lane & 15)][(lane >> 4) * 8];
    #pragma unroll
    for (int nt = 0; nt < 4; ++nt)
      b[nt] = *(const bf16x8*)&Bs[wn * 64 + nt * 16 + (lane & 15)][(lane >> 4) * 8];
    #pragma unroll
    for (int mt = 0; mt < 4; ++mt)
      #pragma unroll
      for (int nt = 0; nt < 4; ++nt)
        acc[mt][nt] = __builtin_amdgcn_mfma_f32_16x16x32_bf16(a[mt], b[nt], acc[mt][nt], 0, 0, 0);
  }

  #pragma unroll
  for (int nt = 0; nt < 4; ++nt) {
    int col = wn * 64 + nt * 16 + (lane & 15);
    float bias = b1[col];
    #pragma unroll
    for (int mt = 0; mt < 4; ++mt) {
      #pragma unroll
      for (int i = 0; i < 4; ++i) {
        long row = m0 + wm * 64 + mt * 16 + (lane >> 4) * 4 + i;
        if (row < N_NODES) H1[row * N_HID + col] = f2bf(acc[mt][nt][i] + bias);
      }
    }
  }
}

// ---------------- SPMM1 + relu: H1r = bf16(relu(A @ H1)), 4-deep gather pipeline ----
__global__ __launch_bounds__(256) void k_spmm1(const int* __restrict__ row_ptr,
                                               const int2* __restrict__ cw,
                                               const unsigned short* __restrict__ H1,
                                               unsigned short* __restrict__ H1r) {
  int r = blockIdx.x * 4 + (threadIdx.x >> 6);
  int lane = threadIdx.x & 63;
  if (r >= N_NODES) return;
  int s = row_ptr[r], e = row_ptr[r + 1];
  float a0 = 0.f, a1 = 0.f, a2 = 0.f, a3 = 0.f;
  const unsigned short* Hb = H1 + lane * 4;
  int i = s;
  for (; i + 4 <= e; i += 4) {
    int2 c0 = cw[i + 0];
    int2 c1 = cw[i + 1];
    int2 c2 = cw[i + 2];
    int2 c3 = cw[i + 3];
    u16x4 h0 = *(const u16x4*)(Hb + (long)c0.x * N_HID);
    u16x4 h1 = *(const u16x4*)(Hb + (long)c1.x * N_HID);
    u16x4 h2 = *(const u16x4*)(Hb + (long)c2.x * N_HID);
    u16x4 h3 = *(const u16x4*)(Hb + (long)c3.x * N_HID);
    float w0 = __int_as_float(c0.y);
    float w1 = __int_as_float(c1.y);
    float w2 = __int_as_float(c2.y);
    float w3 = __int_as_float(c3.y);
    a0 += w0 * bf2f(h0[0]); a1 += w0 * bf2f(h0[1]); a2 += w0 * bf2f(h0[2]); a3 += w0 * bf2f(h0[3]);
    a0 += w1 * bf2f(h1[0]); a1 += w1 * bf2f(h1[1]); a2 += w1 * bf2f(h1[2]); a3 += w1 * bf2f(h1[3]);
    a0 += w2 * bf2f(h2[0]); a1 += w2 * bf2f(h2[1]); a2 += w2 * bf2f(h2[2]); a3 += w2 * bf2f(h2[3]);
    a0 += w3 * bf2f(h3[0]); a1 += w3 * bf2f(h3[1]); a2 += w3 * bf2f(h3[2]); a3 += w3 * bf2f(h3[3]);
  }
  for (; i < e; ++i) {
    int2 cwv = cw[i];
    float w = __int_as_float(cwv.y);
    u16x4 hv = *(const u16x4*)(Hb + (long)cwv.x * N_HID);
    a0 += w * bf2f(hv[0]);
    a1 += w * bf2f(hv[1]);
    a2 += w * bf2f(hv[2]);
    a3 += w * bf2f(hv[3]);
  }
  u16x4 o;
  o[0] = f2bf(fmaxf(a0, 0.f));
  o[1] = f2bf(fmaxf(a1, 0.f));
  o[2] = f2bf(fmaxf(a2, 0.f));
  o[3] = f2bf(fmaxf(a3, 0.f));
  *(u16x4*)(H1r + (long)r * N_HID + lane * 4) = o;
}

// ---------------- GEMM2: H2 = H1r @ W2 + b2, MFMA, N padded to 48 ----------------
// 256 threads = 4 waves, tile 128x48, BK=32
__global__ __launch_bounds__(256) void k_gemm2(const unsigned short* __restrict__ H1r,
                                               const unsigned short* __restrict__ W2t,
                                               const float* __restrict__ b2,
                                               float* __restrict__ H2) {
  __shared__ unsigned short As[128][32];
  __shared__ unsigned short Bs[48][32];
  const int t = threadIdx.x;
  const int lane = t & 63;
  const int wid = t >> 6;                   // wave -> 32-row block
  const long m0 = (long)blockIdx.x * 128;
  f32x4 acc[2][3] = {};

  for (int k0 = 0; k0 < N_HID; k0 += 32) {
    __syncthreads();
    #pragma unroll
    for (int p = 0; p < 2; ++p) {
      int u = t + p * 256;
      int rr = u >> 2, kk = (u & 3) * 8;
      long gr = m0 + rr;
      u16x8 v = {};
      if (gr < N_NODES) v = *(const u16x8*)(H1r + gr * N_HID + k0 + kk);
      *(u16x8*)&As[rr][kk] = v;
    }
    if (t < 192) {
      int rr = t >> 2, kk = (t & 3) * 8;
      *(u16x8*)&Bs[rr][kk] = *(const u16x8*)(W2t + (long)rr * N_HID + k0 + kk);
    }
    __syncthreads();

    bf16x8 a[2], b[3];
    #pragma unroll
    for (int mt = 0; mt < 2; ++mt)
      a[mt] = *(const bf16x8*)&As[wid * 32 + mt * 16 + (lane & 15)][(lane >> 4) * 8];
    #pragma unroll
    for (int nt = 0; nt < 3; ++nt)
      b[nt] = *(const bf16x8*)&Bs[nt * 16 + (lane & 15)][(lane >> 4) * 8];
    #pragma unroll
    for (int mt = 0; mt < 2; ++mt)
      #pragma unroll
      for (int nt = 0; nt < 3; ++nt)
        acc[mt][nt] = __builtin_amdgcn_mfma_f32_16x16x32_bf16(a[mt], b[nt], acc[mt][nt], 0, 0, 0);
  }

  #pragma unroll
  for (int nt = 0; nt < 3; ++nt) {
    int col = nt * 16 + (lane & 15);
    if (col < N_CLASS) {
      float bias = b2[col];
      #pragma unroll
      for (int mt = 0; mt < 2; ++mt) {
        #pragma unroll
        for (int i = 0; i < 4; ++i) {
          long row = m0 + wid * 32 + mt * 16 + (lane >> 4) * 4 + i;
          if (row < N_NODES) H2[row * N_CLASS + col] = acc[mt][nt][i] + bias;
        }
      }
    }
  }
}

// ---------------- SPMM2 + log_softmax fused, 4-deep gather pipeline ----------------
__global__ __launch_bounds__(256) void k_spmm2_lsm(const int* __restrict__ row_ptr,
                                                   const int2* __restrict__ cw,
                                                   const float* __restrict__ H2,
                                                   float* __restrict__ out) {
  int r = blockIdx.x * 4 + (threadIdx.x >> 6);
  int lane = threadIdx.x & 63;
  if (r >= N_NODES) return;
  int s = row_ptr[r], e = row_ptr[r + 1];
  float acc = 0.f;
  const bool act = lane < N_CLASS;
  int i = s;
  for (; i + 4 <= e; i += 4) {
    int2 c0 = cw[i + 0];
    int2 c1 = cw[i + 1];
    int2 c2 = cw[i + 2];
    int2 c3 = cw[i + 3];
    float h0 = 0.f, h1 = 0.f, h2 = 0.f, h3 = 0.f;
    if (act) {
      h0 = H2[(long)c0.x * N_CLASS + lane];
      h1 = H2[(long)c1.x * N_CLASS + lane];
      h2 = H2[(long)c2.x * N_CLASS + lane];
      h3 = H2[(long)c3.x * N_CLASS + lane];
    }
    acc += __int_as_float(c0.y) * h0;
    acc += __int_as_float(c1.y) * h1;
    acc += __int_as_float(c2.y) * h2;
    acc += __int_as_float(c3.y) * h3;
  }
  for (; i < e; ++i) {
    int2 cwv = cw[i];
    if (act) acc += __int_as_float(cwv.y) * H2[(long)cwv.x * N_CLASS + lane];
  }
  float v = act ? acc : -INFINITY;
  float m = v;
  #pragma unroll
  for (int d = 32; d > 0; d >>= 1) m = fmaxf(m, __shfl_xor(m, d));
  float ex = act ? __expf(v - m) : 0.f;
  float ssum = ex;
  #pragma unroll
  for (int d = 32; d > 0; d >>= 1) ssum += __shfl_xor(ssum, d);
  float ls = __logf(ssum);
  if (act) out[(long)r * N_CLASS + lane] = v - m - ls;
}

extern "C" void kernel_launch(void* const* d_in, const int* in_sizes, int n_in,
                              void* d_out, int out_size, void* d_ws, size_t ws_size,
                              hipStream_t stream) {
  (void)in_sizes; (void)n_in; (void)out_size; (void)ws_size;
  const float* X  = (const float*)d_in[0];
  const int*   EI = (const int*)d_in[1];
  const float* EW = (const float*)d_in[2];
  const float* W1 = (const float*)d_in[3];
  const float* b1 = (const float*)d_in[4];
  const float* W2 = (const float*)d_in[5];
  const float* b2 = (const float*)d_in[6];
  float* out = (float*)d_out;

  char* p = (char*)d_ws;
  auto take = [&](size_t bytes) {
    char* r = p;
    p += (bytes + 511) & ~(size_t)511;
    return r;
  };
  unsigned short* W1t   = (unsigned short*)take((size_t)N_HID * N_FEAT * 2);
  unsigned short* W2t   = (unsigned short*)take((size_t)48 * N_HID * 2);
  int*            cnt   = (int*)take((size_t)N_NODES * 4);
  int*            rp    = (int*)take((size_t)(N_NODES + 1) * 4);
  int*            cur   = (int*)take((size_t)(N_NODES + 1) * 4);
  int*            bsum  = (int*)take((size_t)128 * 4);
  int*            boffs = (int*)take((size_t)128 * 4);
  int2*           cw    = (int2*)take((size_t)N_EDGES * 8);
  unsigned short* H1    = (unsigned short*)take((size_t)N_NODES * N_HID * 2);
  unsigned short* H1r   = (unsigned short*)take((size_t)N_NODES * N_HID * 2);
  float*          H2    = (float*)take((size_t)N_NODES * N_CLASS * 4);

  const int NB_SCAN = (N_NODES + 1023) / 1024;     // 98

  hipMemsetAsync(cnt, 0, (size_t)N_NODES * 4, stream);
  k_w1t<<<(N_HID * N_FEAT + 255) / 256, 256, 0, stream>>>(W1, W1t);
  k_w2t<<<(48 * N_HID + 255) / 256, 256, 0, stream>>>(W2, W2t);
  k_hist<<<(N_EDGES + 255) / 256, 256, 0, stream>>>(EI, cnt);
  k_scan_a<<<NB_SCAN, 1024, 0, stream>>>(cnt, rp, bsum);
  k_scan_b<<<1, 128, 0, stream>>>(bsum, boffs, rp);
  k_scan_c<<<(N_NODES + 255) / 256, 256, 0, stream>>>(rp, cur, boffs);
  k_scatter<<<(N_EDGES + 255) / 256, 256, 0, stream>>>(EI, EW, cur, cw);
  k_gemm1<<<(N_NODES + 127) / 128, 512, 0, stream>>>(X, W1t, b1, H1);
  k_spmm1<<<(N_NODES + 3) / 4, 256, 0, stream>>>(rp, cw, H1, H1r);
  k_gemm2<<<(N_NODES + 127) / 128, 256, 0, stream>>>(H1r, W2t, b2, H2);
  k_spmm2_lsm<<<(N_NODES + 3) / 4, 256, 0, stream>>>(rp, cw, H2, out);
}

// Round 4
// 437.786 us; speedup vs baseline: 1.9102x; 1.0780x over previous
//
#include <hip/hip_runtime.h>
#include <stdint.h>

#define N_NODES 100000
#define N_EDGES 1600000
#define N_FEAT 512
#define N_HID 256
#define N_CLASS 40
#define H2S 48                      // padded H2 row stride (floats): 192B = 3 full lines

typedef float f32x4 __attribute__((ext_vector_type(4)));
typedef __bf16 bf16x8 __attribute__((ext_vector_type(8)));
typedef unsigned short u16x4 __attribute__((ext_vector_type(4)));
typedef unsigned short u16x8 __attribute__((ext_vector_type(8)));

__device__ __forceinline__ unsigned short f2bf(float f) {
  unsigned int u = __float_as_uint(f);
  unsigned int r = (u + 0x7FFFu + ((u >> 16) & 1u)) >> 16;
  return (unsigned short)r;
}
__device__ __forceinline__ float bf2f(unsigned short s) {
  return __uint_as_float(((unsigned int)s) << 16);
}

// ---------------- preamble: W1 transpose+cvt | W2 transpose+cvt | hist(+rank) ------
#define HIST_BLOCKS 1563            // ceil(1.6e6 / 1024), 4 edges/thread
#define W1T_BLOCKS  512             // 256*512/256
#define W2T_BLOCKS  48              // 48*256/256
__global__ __launch_bounds__(256) void k_pre(const float* __restrict__ W1,
                                             const float* __restrict__ W2,
                                             const int* __restrict__ ei,
                                             unsigned short* __restrict__ W1t,
                                             unsigned short* __restrict__ W2t,
                                             int* __restrict__ cnt,
                                             int* __restrict__ rank) {
  const int bid = blockIdx.x, tid = threadIdx.x;
  if (bid < HIST_BLOCKS) {
    #pragma unroll
    for (int k = 0; k < 4; ++k) {
      int e = bid * 1024 + k * 256 + tid;
      if (e < N_EDGES) rank[e] = atomicAdd(&cnt[ei[e]], 1);
    }
  } else if (bid < HIST_BLOCKS + W1T_BLOCKS) {
    int gid = (bid - HIST_BLOCKS) * 256 + tid;       // W1t[n][k], n in [0,256), k in [0,512)
    int n = gid >> 9, k = gid & 511;
    W1t[gid] = f2bf(W1[(long)k * N_HID + n]);
  } else {
    int gid = (bid - HIST_BLOCKS - W1T_BLOCKS) * 256 + tid;  // W2t[n][k], n pad to 48
    int n = gid >> 8, k = gid & 255;
    W2t[gid] = (n < N_CLASS) ? f2bf(W2[(long)k * N_CLASS + n]) : (unsigned short)0;
  }
}

// ---------------- scan (3 passes) ----------------
__global__ __launch_bounds__(1024) void k_scan_a(const int* __restrict__ cnt,
                                                 int* __restrict__ rp,
                                                 int* __restrict__ bsum) {
  __shared__ int sm[1024];
  const int tid = threadIdx.x;
  const int i = blockIdx.x * 1024 + tid;
  int v = (i < N_NODES) ? cnt[i] : 0;
  sm[tid] = v;
  __syncthreads();
  #pragma unroll
  for (int d = 1; d < 1024; d <<= 1) {
    int t = (tid >= d) ? sm[tid - d] : 0;
    __syncthreads();
    sm[tid] += t;
    __syncthreads();
  }
  if (i < N_NODES) rp[i] = sm[tid] - v;
  if (tid == 1023) bsum[blockIdx.x] = sm[1023];
}

__global__ __launch_bounds__(128) void k_scan_b(const int* __restrict__ bsum,
                                                int* __restrict__ boffs,
                                                int* __restrict__ rp) {
  __shared__ int sm[128];
  const int tid = threadIdx.x;
  const int nb = (N_NODES + 1023) >> 10;
  int v = (tid < nb) ? bsum[tid] : 0;
  sm[tid] = v;
  __syncthreads();
  #pragma unroll
  for (int d = 1; d < 128; d <<= 1) {
    int t = (tid >= d) ? sm[tid - d] : 0;
    __syncthreads();
    sm[tid] += t;
    __syncthreads();
  }
  boffs[tid] = sm[tid] - v;
  if (tid == 127) rp[N_NODES] = sm[127];
}

__global__ void k_scan_c(int* __restrict__ rp, const int* __restrict__ boffs) {
  int i = blockIdx.x * 256 + threadIdx.x;
  if (i >= N_NODES) return;
  rp[i] += boffs[i >> 10];
}

// ---------------- fused: GEMM1 (even blocks) + scatter (odd blocks) ----------------
// gemm role: 512 thr = 8 waves (2m x 4n), tile 128x256, BK=32, 2-phase reg pipeline
// scatter role: 512 thr x 4 edges, no atomics (rank precomputed)
#define NG1 782                     // ceil(100000/128) gemm blocks; same count scatter blocks
__global__ __launch_bounds__(512) void k_fused1(const float* __restrict__ X,
                                                const unsigned short* __restrict__ W1t,
                                                const float* __restrict__ b1,
                                                unsigned short* __restrict__ H1,
                                                const int* __restrict__ ei,
                                                const float* __restrict__ ew,
                                                const int* __restrict__ rank,
                                                const int* __restrict__ rp,
                                                int2* __restrict__ cw) {
  __shared__ unsigned short As[128][40];   // +8 pad: bank-conflict-free
  __shared__ unsigned short Bs[256][40];
  const int t = threadIdx.x;

  if (blockIdx.x & 1) {                    // ---- scatter role ----
    int sb = blockIdx.x >> 1;
    #pragma unroll
    for (int k = 0; k < 4; ++k) {
      int e = sb * 2048 + k * 512 + t;
      if (e < N_EDGES) {
        int r = ei[e];
        int pos = rp[r] + rank[e];
        cw[pos] = make_int2(ei[N_EDGES + e], __float_as_int(ew[e]));
      }
    }
    return;
  }

  // ---- gemm role ----
  const int gb = blockIdx.x >> 1;
  const int lane = t & 63;
  const int wid = t >> 6;
  const int wm = wid >> 2, wn = wid & 3;
  const long m0 = (long)gb * 128;

  f32x4 acc[4][4] = {};
  const int ar = t >> 2;
  const int ak = (t & 3) * 8;
  const long arow = m0 + ar;
  const bool avalid = arow < N_NODES;
  const float* xs = X + arow * N_FEAT;
  const unsigned short* ws0 = W1t + (long)ar * N_FEAT;
  const unsigned short* ws1 = W1t + (long)(ar + 128) * N_FEAT;

  f32x4 xa = {}, xb = {};
  if (avalid) { xa = *(const f32x4*)(xs + ak); xb = *(const f32x4*)(xs + ak + 4); }
  u16x8 wa = *(const u16x8*)(ws0 + ak);
  u16x8 wb = *(const u16x8*)(ws1 + ak);

  for (int k0 = 0; k0 < N_FEAT; k0 += 32) {
    __syncthreads();                       // prev iter's frag reads done
    u16x8 ap;
    ap[0] = f2bf(xa[0]); ap[1] = f2bf(xa[1]); ap[2] = f2bf(xa[2]); ap[3] = f2bf(xa[3]);
    ap[4] = f2bf(xb[0]); ap[5] = f2bf(xb[1]); ap[6] = f2bf(xb[2]); ap[7] = f2bf(xb[3]);
    *(u16x8*)&As[ar][ak] = ap;
    *(u16x8*)&Bs[ar][ak] = wa;
    *(u16x8*)&Bs[ar + 128][ak] = wb;
    __syncthreads();

    if (k0 + 32 < N_FEAT) {                // issue next tile's loads; MFMA hides latency
      int ko = k0 + 32 + ak;
      if (avalid) { xa = *(const f32x4*)(xs + ko); xb = *(const f32x4*)(xs + ko + 4); }
      wa = *(const u16x8*)(ws0 + ko);
      wb = *(const u16x8*)(ws1 + ko);
    }

    bf16x8 a[4], b[4];
    #pragma unroll
    for (int mt = 0; mt < 4; ++mt)
      a[mt] = *(const bf16x8*)&As[wm * 64 + mt * 16 + (lane & 15)][(lane >> 4) * 8];
    #pragma unroll
    for (int nt = 0; nt < 4; ++nt)
      b[nt] = *(const bf16x8*)&Bs[wn * 64 + nt * 16 + (lane & 15)][(lane >> 4) * 8];
    #pragma unroll
    for (int mt = 0; mt < 4; ++mt)
      #pragma unroll
      for (int nt = 0; nt < 4; ++nt)
        acc[mt][nt] = __builtin_amdgcn_mfma_f32_16x16x32_bf16(a[mt], b[nt], acc[mt][nt], 0, 0, 0);
  }

  #pragma unroll
  for (int nt = 0; nt < 4; ++nt) {
    int col = wn * 64 + nt * 16 + (lane & 15);
    float bias = b1[col];
    #pragma unroll
    for (int mt = 0; mt < 4; ++mt) {
      #pragma unroll
      for (int i = 0; i < 4; ++i) {
        long row = m0 + wm * 64 + mt * 16 + (lane >> 4) * 4 + i;
        if (row < N_NODES) H1[row * N_HID + col] = f2bf(acc[mt][nt][i] + bias);
      }
    }
  }
}

// ---------------- SPMM1 + relu: H1r = bf16(relu(A @ H1)), 8-deep gather pipeline ----
__global__ __launch_bounds__(256) void k_spmm1(const int* __restrict__ row_ptr,
                                               const int2* __restrict__ cw,
                                               const unsigned short* __restrict__ H1,
                                               unsigned short* __restrict__ H1r) {
  int r = blockIdx.x * 4 + (threadIdx.x >> 6);
  int lane = threadIdx.x & 63;
  if (r >= N_NODES) return;
  int s = row_ptr[r], e = row_ptr[r + 1];
  float a0 = 0.f, a1 = 0.f, a2 = 0.f, a3 = 0.f;
  const unsigned short* Hb = H1 + lane * 4;
  int i = s;
  for (; i + 8 <= e; i += 8) {
    int2 c0 = cw[i + 0]; int2 c1 = cw[i + 1]; int2 c2 = cw[i + 2]; int2 c3 = cw[i + 3];
    int2 c4 = cw[i + 4]; int2 c5 = cw[i + 5]; int2 c6 = cw[i + 6]; int2 c7 = cw[i + 7];
    u16x4 h0 = *(const u16x4*)(Hb + (long)c0.x * N_HID);
    u16x4 h1 = *(const u16x4*)(Hb + (long)c1.x * N_HID);
    u16x4 h2 = *(const u16x4*)(Hb + (long)c2.x * N_HID);
    u16x4 h3 = *(const u16x4*)(Hb + (long)c3.x * N_HID);
    u16x4 h4 = *(const u16x4*)(Hb + (long)c4.x * N_HID);
    u16x4 h5 = *(const u16x4*)(Hb + (long)c5.x * N_HID);
    u16x4 h6 = *(const u16x4*)(Hb + (long)c6.x * N_HID);
    u16x4 h7 = *(const u16x4*)(Hb + (long)c7.x * N_HID);
    float w0 = __int_as_float(c0.y), w1 = __int_as_float(c1.y);
    float w2 = __int_as_float(c2.y), w3 = __int_as_float(c3.y);
    float w4 = __int_as_float(c4.y), w5 = __int_as_float(c5.y);
    float w6 = __int_as_float(c6.y), w7 = __int_as_float(c7.y);
    a0 += w0 * bf2f(h0[0]); a1 += w0 * bf2f(h0[1]); a2 += w0 * bf2f(h0[2]); a3 += w0 * bf2f(h0[3]);
    a0 += w1 * bf2f(h1[0]); a1 += w1 * bf2f(h1[1]); a2 += w1 * bf2f(h1[2]); a3 += w1 * bf2f(h1[3]);
    a0 += w2 * bf2f(h2[0]); a1 += w2 * bf2f(h2[1]); a2 += w2 * bf2f(h2[2]); a3 += w2 * bf2f(h2[3]);
    a0 += w3 * bf2f(h3[0]); a1 += w3 * bf2f(h3[1]); a2 += w3 * bf2f(h3[2]); a3 += w3 * bf2f(h3[3]);
    a0 += w4 * bf2f(h4[0]); a1 += w4 * bf2f(h4[1]); a2 += w4 * bf2f(h4[2]); a3 += w4 * bf2f(h4[3]);
    a0 += w5 * bf2f(h5[0]); a1 += w5 * bf2f(h5[1]); a2 += w5 * bf2f(h5[2]); a3 += w5 * bf2f(h5[3]);
    a0 += w6 * bf2f(h6[0]); a1 += w6 * bf2f(h6[1]); a2 += w6 * bf2f(h6[2]); a3 += w6 * bf2f(h6[3]);
    a0 += w7 * bf2f(h7[0]); a1 += w7 * bf2f(h7[1]); a2 += w7 * bf2f(h7[2]); a3 += w7 * bf2f(h7[3]);
  }
  for (; i < e; ++i) {
    int2 cwv = cw[i];
    float w = __int_as_float(cwv.y);
    u16x4 hv = *(const u16x4*)(Hb + (long)cwv.x * N_HID);
    a0 += w * bf2f(hv[0]);
    a1 += w * bf2f(hv[1]);
    a2 += w * bf2f(hv[2]);
    a3 += w * bf2f(hv[3]);
  }
  u16x4 o;
  o[0] = f2bf(fmaxf(a0, 0.f));
  o[1] = f2bf(fmaxf(a1, 0.f));
  o[2] = f2bf(fmaxf(a2, 0.f));
  o[3] = f2bf(fmaxf(a3, 0.f));
  *(u16x4*)(H1r + (long)r * N_HID + lane * 4) = o;
}

// ---------------- GEMM2: H2[.][48] = H1r @ W2 + b2, MFMA ----------------
__global__ __launch_bounds__(256) void k_gemm2(const unsigned short* __restrict__ H1r,
                                               const unsigned short* __restrict__ W2t,
                                               const float* __restrict__ b2,
                                               float* __restrict__ H2) {
  __shared__ unsigned short As[128][40];
  __shared__ unsigned short Bs[48][40];
  const int t = threadIdx.x;
  const int lane = t & 63;
  const int wid = t >> 6;
  const long m0 = (long)blockIdx.x * 128;
  f32x4 acc[2][3] = {};

  for (int k0 = 0; k0 < N_HID; k0 += 32) {
    __syncthreads();
    #pragma unroll
    for (int p = 0; p < 2; ++p) {
      int u = t + p * 256;
      int rr = u >> 2, kk = (u & 3) * 8;
      long gr = m0 + rr;
      u16x8 v = {};
      if (gr < N_NODES) v = *(const u16x8*)(H1r + gr * N_HID + k0 + kk);
      *(u16x8*)&As[rr][kk] = v;
    }
    if (t < 192) {
      int rr = t >> 2, kk = (t & 3) * 8;
      *(u16x8*)&Bs[rr][kk] = *(const u16x8*)(W2t + (long)rr * N_HID + k0 + kk);
    }
    __syncthreads();

    bf16x8 a[2], b[3];
    #pragma unroll
    for (int mt = 0; mt < 2; ++mt)
      a[mt] = *(const bf16x8*)&As[wid * 32 + mt * 16 + (lane & 15)][(lane >> 4) * 8];
    #pragma unroll
    for (int nt = 0; nt < 3; ++nt)
      b[nt] = *(const bf16x8*)&Bs[nt * 16 + (lane & 15)][(lane >> 4) * 8];
    #pragma unroll
    for (int mt = 0; mt < 2; ++mt)
      #pragma unroll
      for (int nt = 0; nt < 3; ++nt)
        acc[mt][nt] = __builtin_amdgcn_mfma_f32_16x16x32_bf16(a[mt], b[nt], acc[mt][nt], 0, 0, 0);
  }

  #pragma unroll
  for (int nt = 0; nt < 3; ++nt) {
    int col = nt * 16 + (lane & 15);
    if (col < N_CLASS) {
      float bias = b2[col];
      #pragma unroll
      for (int mt = 0; mt < 2; ++mt) {
        #pragma unroll
        for (int i = 0; i < 4; ++i) {
          long row = m0 + wid * 32 + mt * 16 + (lane >> 4) * 4 + i;
          if (row < N_NODES) H2[row * H2S + col] = acc[mt][nt][i] + bias;
        }
      }
    }
  }
}

// ---------------- SPMM2 + log_softmax fused, 4-deep gather pipeline ----------------
__global__ __launch_bounds__(256) void k_spmm2_lsm(const int* __restrict__ row_ptr,
                                                   const int2* __restrict__ cw,
                                                   const float* __restrict__ H2,
                                                   float* __restrict__ out) {
  int r = blockIdx.x * 4 + (threadIdx.x >> 6);
  int lane = threadIdx.x & 63;
  if (r >= N_NODES) return;
  int s = row_ptr[r], e = row_ptr[r + 1];
  float acc = 0.f;
  const bool act = lane < N_CLASS;
  int i = s;
  for (; i + 4 <= e; i += 4) {
    int2 c0 = cw[i + 0];
    int2 c1 = cw[i + 1];
    int2 c2 = cw[i + 2];
    int2 c3 = cw[i + 3];
    float h0 = 0.f, h1 = 0.f, h2 = 0.f, h3 = 0.f;
    if (act) {
      h0 = H2[(long)c0.x * H2S + lane];
      h1 = H2[(long)c1.x * H2S + lane];
      h2 = H2[(long)c2.x * H2S + lane];
      h3 = H2[(long)c3.x * H2S + lane];
    }
    acc += __int_as_float(c0.y) * h0;
    acc += __int_as_float(c1.y) * h1;
    acc += __int_as_float(c2.y) * h2;
    acc += __int_as_float(c3.y) * h3;
  }
  for (; i < e; ++i) {
    int2 cwv = cw[i];
    if (act) acc += __int_as_float(cwv.y) * H2[(long)cwv.x * H2S + lane];
  }
  float v = act ? acc : -INFINITY;
  float m = v;
  #pragma unroll
  for (int d = 32; d > 0; d >>= 1) m = fmaxf(m, __shfl_xor(m, d));
  float ex = act ? __expf(v - m) : 0.f;
  float ssum = ex;
  #pragma unroll
  for (int d = 32; d > 0; d >>= 1) ssum += __shfl_xor(ssum, d);
  float ls = __logf(ssum);
  if (act) out[(long)r * N_CLASS + lane] = v - m - ls;
}

extern "C" void kernel_launch(void* const* d_in, const int* in_sizes, int n_in,
                              void* d_out, int out_size, void* d_ws, size_t ws_size,
                              hipStream_t stream) {
  (void)in_sizes; (void)n_in; (void)out_size; (void)ws_size;
  const float* X  = (const float*)d_in[0];
  const int*   EI = (const int*)d_in[1];
  const float* EW = (const float*)d_in[2];
  const float* W1 = (const float*)d_in[3];
  const float* b1 = (const float*)d_in[4];
  const float* W2 = (const float*)d_in[5];
  const float* b2 = (const float*)d_in[6];
  float* out = (float*)d_out;

  char* p = (char*)d_ws;
  auto take = [&](size_t bytes) {
    char* r = p;
    p += (bytes + 511) & ~(size_t)511;
    return r;
  };
  unsigned short* W1t   = (unsigned short*)take((size_t)N_HID * N_FEAT * 2);
  unsigned short* W2t   = (unsigned short*)take((size_t)48 * N_HID * 2);
  int*            cnt   = (int*)take((size_t)N_NODES * 4);
  int*            rp    = (int*)take((size_t)(N_NODES + 1) * 4);
  int*            bsum  = (int*)take((size_t)128 * 4);
  int*            boffs = (int*)take((size_t)128 * 4);
  int*            rank  = (int*)take((size_t)N_EDGES * 4);
  int2*           cw    = (int2*)take((size_t)N_EDGES * 8);
  unsigned short* H1    = (unsigned short*)take((size_t)N_NODES * N_HID * 2);
  unsigned short* H1r   = (unsigned short*)take((size_t)N_NODES * N_HID * 2);
  float*          H2    = (float*)take((size_t)N_NODES * H2S * 4);

  const int NB_SCAN = (N_NODES + 1023) / 1024;     // 98

  hipMemsetAsync(cnt, 0, (size_t)N_NODES * 4, stream);
  k_pre<<<HIST_BLOCKS + W1T_BLOCKS + W2T_BLOCKS, 256, 0, stream>>>(W1, W2, EI, W1t, W2t, cnt, rank);
  k_scan_a<<<NB_SCAN, 1024, 0, stream>>>(cnt, rp, bsum);
  k_scan_b<<<1, 128, 0, stream>>>(bsum, boffs, rp);
  k_scan_c<<<(N_NODES + 255) / 256, 256, 0, stream>>>(rp, boffs);
  k_fused1<<<2 * NG1, 512, 0, stream>>>(X, W1t, b1, H1, EI, EW, rank, rp, cw);
  k_spmm1<<<(N_NODES + 3) / 4, 256, 0, stream>>>(rp, cw, H1, H1r);
  k_gemm2<<<(N_NODES + 127) / 128, 256, 0, stream>>>(H1r, W2t, b2, H2);
  k_spmm2_lsm<<<(N_NODES + 3) / 4, 256, 0, stream>>>(rp, cw, H2, out);
}